// Round 9
// baseline (1032.081 us; speedup 1.0000x reference)
//
#include <hip/hip_runtime.h>
#include <math.h>

// ---------------------------------------------------------------------------
// FNO2d forward, MFMA everywhere, channels-last activations.
// h [b][x][y][i] bf16. k_conv split into o-halves (acc=32 regs, 8 blocks/CU);
// sibling halves share the same 32KB h slice -> blockIdx swizzled so both
// land on the SAME XCD (blk%8 round-robin assumption) and dispatch within 8
// blocks of each other, making the second h read an L2 hit instead of a
// second HBM fetch (round-8 counter: FETCH doubled without this).
// Spectral chain: coalesced writes everywhere; scatters are L2-hot reads.
// Workspace: identical layout to round 7/8 (~164.2 MiB).
// ---------------------------------------------------------------------------

typedef unsigned int   u32;
typedef unsigned short u16;
typedef __attribute__((ext_vector_type(8))) __bf16 bf16x8;
typedef __attribute__((ext_vector_type(4))) float  f32x4;

constexpr long F1_B  = 134217728;
constexpr long G_B   = 150994944;
constexpr long F2_B  = 167772160;
constexpr long CC_B  = 169869312;
constexpr long WF_B  = 171966464;
constexpr long WXI_B = 171999232;
constexpr long TWF_B = 172032000;
constexpr long BAS_B = 172048384;
constexpr long WSP_B = 172064768;

constexpr int HOP = 76;   // full-tile row pad (u16) for lift/head kernels
constexpr int HO2 = 36;   // o-half row pad (u16): 72 B, 8B-aligned rows

union BU { uint2 u2[2]; uint4 u4; bf16x8 v; u16 s[8]; };

// fast gelu: |erf err| <= 1.5e-7 (A&S 7.1.26); bf16 storage noise dominates.
__device__ __forceinline__ float gelu_fast(float v) {
    const float ax = fabsf(v) * 0.70710678118654752440f;
    const float t = __builtin_amdgcn_rcpf(fmaf(0.3275911f, ax, 1.0f));
    float poly = fmaf(1.061405429f, t, -1.453152027f);
    poly = fmaf(poly, t, 1.421413741f);
    poly = fmaf(poly, t, -0.284496736f);
    poly = fmaf(poly, t, 0.254829592f);
    poly *= t;
    const float pe = poly * __expf(-ax * ax);      // = 1 - erf(ax)
    const float w = (v >= 0.0f) ? (2.0f - pe) : pe;
    return 0.5f * v * w;
}
__device__ __forceinline__ float bflo(u32 u) { return __uint_as_float(u << 16); }
__device__ __forceinline__ float bfhi(u32 u) { return __uint_as_float(u & 0xffff0000u); }
__device__ __forceinline__ u16 f2bf(float f) {            // fp32 -> bf16 RNE
    u32 u = __float_as_uint(f);
    u += 0x7fffu + ((u >> 16) & 1u);
    return (u16)(u >> 16);
}
__device__ __forceinline__ u32 pack2bf(float a, float b) {
    return (u32)f2bf(a) | ((u32)f2bf(b) << 16);
}

// --- tables ----------------------------------------------------------------
__global__ __launch_bounds__(256) void k_tab(float* __restrict__ wf,
                                             float* __restrict__ wxi,
                                             u16* __restrict__ twf,
                                             u16* __restrict__ bas) {
    const int t = blockIdx.x * 256 + threadIdx.x;   // 0..24575
    if (t < 4096) {               // wf[x][k][2] = (cos, -sin)(2*pi*k*x/256)
        const int y = t >> 4, k = t & 15;
        const int m = (k * y) & 255;
        double s, c; sincospi((double)m / 128.0, &s, &c);
        wf[t * 2] = (float)c; wf[t * 2 + 1] = (float)(-s);
    } else if (t < 8192) {        // wxi[k1][x][2] = (cos, +sin)
        const int u = t - 4096;
        const int k1 = u >> 8, x = u & 255;
        const int m = (k1 * x) & 255;
        double s, c; sincospi((double)m / 128.0, &s, &c);
        wxi[u * 2] = (float)c; wxi[u * 2 + 1] = (float)s;
    } else if (t < 16384) {       // twf[k2c][y]: re=cos, im=-sin
        const int u = t - 8192;
        const int kc = u >> 8, y = u & 255;
        const int k2 = kc >> 1;
        const int m = (k2 * y) & 255;
        double s, c; sincospi((double)m / 128.0, &s, &c);
        twf[kc * 256 + y] = f2bf((kc & 1) ? (float)(-s) : (float)c);
    } else {                      // bas[y][2k2+c]: c_k2*cos / -c_k2*sin
        const int u = t - 16384;
        const int y = u >> 5, kc = u & 31;
        const int k2 = kc >> 1;
        const int m = (k2 * y) & 255;
        double s, c; sincospi((double)m / 128.0, &s, &c);
        const float cc = (k2 == 0) ? 1.0f : 2.0f;
        bas[y * 32 + kc] = f2bf((kc & 1) ? (float)(-cc * s) : (float)(cc * c));
    }
}

// --- weight split: wsp[w][o][0..63]=hi, [o][64..127]=lo --------------------
__global__ __launch_bounds__(256) void k_wsplit(const float* __restrict__ c1,
                                                const float* __restrict__ c2,
                                                const float* __restrict__ c3,
                                                const float* __restrict__ c4,
                                                const float* __restrict__ f1w,
                                                u16* __restrict__ wsp) {
    const int t = blockIdx.x * 256 + threadIdx.x;   // < 20480
    const int w = t >> 12, p = t & 4095;
    const float* src = (w == 0) ? c1 : (w == 1) ? c2 : (w == 2) ? c3
                     : (w == 3) ? c4 : f1w;
    const float f = src[p];
    const u16 hi = f2bf(f);
    const u16 lo = f2bf(f - __uint_as_float((u32)hi << 16));
    u16* dst = wsp + w * 8192 + (p >> 6) * 128 + (p & 63);
    dst[0]  = hi;
    dst[64] = lo;
}

// --- per-layer transpose: swT[m][p] = sw[p][m] / 65536  (fp32, tiled) ------
__global__ __launch_bounds__(256) void k_swT(const float* __restrict__ sw,
                                             float2* __restrict__ swT) {
    __shared__ float2 tile[64][65];
    const int tid = threadIdx.x;
    const int pt = blockIdx.x >> 2, mt = blockIdx.x & 3;
    const int r = tid >> 2, q = tid & 3;
    const float scale = 1.0f / 65536.0f;
    const float2* src = (const float2*)sw + (long)(pt * 64 + r) * 256 + mt * 64 + q * 16;
    #pragma unroll
    for (int j = 0; j < 16; j++) {
        float2 v = src[j];
        v.x *= scale; v.y *= scale;
        tile[r][q * 16 + j] = v;
    }
    __syncthreads();
    float2* dst = swT + (long)(mt * 64 + r) * 4096 + pt * 64 + q * 16;
    #pragma unroll
    for (int j = 0; j < 16; j++)
        dst[j] = tile[q * 16 + j][r];
}

// --- full-tile DFT-y epilogue (lift): f1 rows from HOyo[y][o], o = 64 ------
__device__ __forceinline__ void f1t_epilogue(const u16* HOyo,
                                             const u16* __restrict__ twf,
                                             u16* __restrict__ f1,
                                             int b, int x, int tid) {
    const int lane = tid & 63, wave = tid >> 6;
    const int quad = lane >> 4, col = lane & 15;
    const int o = wave * 16 + col;
    f32x4 a0 = {0.f, 0.f, 0.f, 0.f}, a1 = {0.f, 0.f, 0.f, 0.f};
    #pragma unroll
    for (int ks = 0; ks < 8; ks++) {
        const int kb = ks * 32 + quad * 8;
        BU bb;
        #pragma unroll
        for (int j = 0; j < 8; j++) bb.s[j] = HOyo[(kb + j) * HOP + o];
        const bf16x8 af0 = *(const bf16x8*)(twf + col * 256 + kb);
        const bf16x8 af1 = *(const bf16x8*)(twf + (16 + col) * 256 + kb);
        a0 = __builtin_amdgcn_mfma_f32_16x16x32_bf16(af0, bb.v, a0, 0, 0, 0);
        a1 = __builtin_amdgcn_mfma_f32_16x16x32_bf16(af1, bb.v, a1, 0, 0, 0);
    }
    u16* dst = f1 + (((long)(b * 64 + o)) * 256 + x) * 32 + quad * 4;
    uint2 w;
    w.x = pack2bf(a0[0], a0[1]); w.y = pack2bf(a0[2], a0[3]);
    *(uint2*)dst = w;
    w.x = pack2bf(a1[0], a1[1]); w.y = pack2bf(a1[2], a1[3]);
    *(uint2*)(dst + 16) = w;
}

// --- lift: h[b][x][y][i] = fc0(x), channels-last, + DFT-y epilogue ---------
__global__ __launch_bounds__(256) void k_lift(const float* __restrict__ xin,
                                              const float* __restrict__ w0,
                                              const float* __restrict__ b0,
                                              u16* __restrict__ h,
                                              const u16* __restrict__ twf,
                                              u16* __restrict__ f1) {
    __shared__ float ws0[192], bs0[64];
    __shared__ u16 HOyo[256 * HOP];
    const int tid = threadIdx.x;
    if (tid < 192) ws0[tid] = w0[tid];
    if (tid < 64)  bs0[tid] = b0[tid];
    __syncthreads();
    const int b = blockIdx.x >> 8, x = blockIdx.x & 255;
    const long pix = (((long)b * 3) * 256 + x) * 256 + tid;
    const float x0 = xin[pix];
    const float x1 = xin[pix + 65536];
    const float x2 = xin[pix + 131072];
    u32 pr[32];
    #pragma unroll
    for (int w = 0; w < 64; w += 2) {
        float v0 = bs0[w], v1 = bs0[w + 1];
        v0 = fmaf(x0, ws0[w * 3],     v0);  v1 = fmaf(x0, ws0[w * 3 + 3], v1);
        v0 = fmaf(x1, ws0[w * 3 + 1], v0);  v1 = fmaf(x1, ws0[w * 3 + 4], v1);
        v0 = fmaf(x2, ws0[w * 3 + 2], v0);  v1 = fmaf(x2, ws0[w * 3 + 5], v1);
        pr[w >> 1] = pack2bf(v0, v1);
    }
    u16* hrow = h + (((long)(b * 256 + x)) << 14) + (long)tid * 64;
    #pragma unroll
    for (int q = 0; q < 8; q++) *(uint4*)(hrow + q * 8) = ((uint4*)pr)[q];
    #pragma unroll
    for (int q = 0; q < 16; q++)
        *(uint2*)(HOyo + tid * HOP + q * 4) = ((uint2*)pr)[q];
    __syncthreads();
    f1t_epilogue(HOyo, twf, f1, b, x, tid);
}

// --- K2: f2[bi][m] = sum_x F1[bi][x][k2] * wf[x][k1]   (m = k1*16+k2) ------
__global__ __launch_bounds__(256) void k_dftx(const u16* __restrict__ f1,
                                              const float* __restrict__ wf,
                                              float* __restrict__ f2) {
    __shared__ u32 fsh[4096];   // [x][16] re/im bf16 pairs
    const int tid = threadIdx.x;
    const uint4* src = (const uint4*)(f1 + (long)blockIdx.x * 8192);
    uint4* dst = (uint4*)fsh;
    #pragma unroll
    for (int q = 0; q < 4; q++) dst[q * 256 + tid] = src[q * 256 + tid];
    __syncthreads();
    const int k1 = tid >> 4, k2 = tid & 15;
    float cr0 = 0, ci0 = 0, cr1 = 0, ci1 = 0;
    for (int x = 0; x < 256; x += 2) {
        const u32 wa = fsh[x * 16 + k2];
        const float2 ta = *(const float2*)(wf + x * 32 + k1 * 2);
        const float Far = bflo(wa), Fai = bfhi(wa);
        cr0 = fmaf(Far, ta.x, fmaf(-Fai, ta.y, cr0));
        ci0 = fmaf(Fai, ta.x, fmaf(Far, ta.y, ci0));
        const u32 wb = fsh[(x + 1) * 16 + k2];
        const float2 tb = *(const float2*)(wf + (x + 1) * 32 + k1 * 2);
        const float Fbr = bflo(wb), Fbi = bfhi(wb);
        cr1 = fmaf(Fbr, tb.x, fmaf(-Fbi, tb.y, cr1));
        ci1 = fmaf(Fbi, tb.x, fmaf(Fbr, tb.y, ci1));
    }
    *(float2*)(f2 + ((long)blockIdx.x * 256 + tid) * 2) =
        make_float2(cr0 + cr1, ci0 + ci1);
}

// --- K3: cc[m][b][o] = sum_i f2[b*64+i][m] * swT[m][i*64+o] ----------------
__global__ __launch_bounds__(256) void k_mode(const float* __restrict__ f2,
                                              const float2* __restrict__ swT,
                                              float* __restrict__ cc) {
    __shared__ float2 wsh[4096];   // [i*64+o], pre-scaled
    __shared__ float2 fsh[1024];   // [b*64+i]
    const int tid = threadIdx.x;
    const int m = blockIdx.x;
    const float2* wsrc = swT + (long)m * 4096;
    for (int p = tid; p < 4096; p += 256) wsh[p] = wsrc[p];
    for (int t = tid; t < 1024; t += 256)
        fsh[t] = *(const float2*)(f2 + ((long)t * 256 + m) * 2);
    __syncthreads();
    const int b = tid >> 4, o0 = (tid & 15) * 4;
    float re[4] = {0, 0, 0, 0}, im[4] = {0, 0, 0, 0};
    for (int i = 0; i < 64; i++) {
        const float2 F = fsh[b * 64 + i];
        #pragma unroll
        for (int oo = 0; oo < 4; oo++) {
            const float2 W = wsh[i * 64 + o0 + oo];
            re[oo] = fmaf(F.x, W.x, fmaf(-F.y, W.y, re[oo]));
            im[oo] = fmaf(F.x, W.y, fmaf(F.y, W.x, im[oo]));
        }
    }
    #pragma unroll
    for (int oo = 0; oo < 4; oo++)
        *(float2*)(cc + ((long)m * 1024 + b * 64 + o0 + oo) * 2) =
            make_float2(re[oo], im[oo]);
}

// --- K4: G[b][x][o][kc]; block = (b, o); cc gather from L2 -----------------
__global__ __launch_bounds__(256) void k_invx(const float* __restrict__ cc,
                                              const float* __restrict__ wxi,
                                              u16* __restrict__ g) {
    __shared__ float2 csh[256];       // [m]
    const int tid = threadIdx.x;
    const int b = blockIdx.x >> 6, o = blockIdx.x & 63;
    csh[tid] = *(const float2*)(cc + ((long)tid * 1024 + b * 64 + o) * 2);
    __syncthreads();
    const int x = tid;
    float ar[16], ai[16];
    #pragma unroll
    for (int k = 0; k < 16; k++) { ar[k] = 0; ai[k] = 0; }
    for (int k1 = 0; k1 < 16; k1++) {
        const float2 t = *(const float2*)(wxi + (k1 * 256 + x) * 2);
        #pragma unroll
        for (int k2 = 0; k2 < 16; k2++) {
            const float2 C = csh[k1 * 16 + k2];
            ar[k2] = fmaf(C.x, t.x, fmaf(-C.y, t.y, ar[k2]));
            ai[k2] = fmaf(C.x, t.y, fmaf(C.y, t.x, ai[k2]));
        }
    }
    u32 wbuf[16];
    #pragma unroll
    for (int k = 0; k < 16; k++) wbuf[k] = pack2bf(ar[k], ai[k]);
    u16* ob = g + ((long)(b * 256 + x) * 64 + o) * 32;   // 64 B, sector-aligned
    #pragma unroll
    for (int q = 0; q < 4; q++) *(uint4*)(ob + q * 8) = ((uint4*)wbuf)[q];
}

// --- K5 (layers 1-3): o-half blocks, XCD-paired swizzle --------------------
__global__ __launch_bounds__(256, 8) void k_conv(u16* __restrict__ h,
                                                 const u16* __restrict__ Gbf,
                                                 const u16* __restrict__ wsp,
                                                 const float* __restrict__ cb,
                                                 const u16* __restrict__ bas,
                                                 const u16* __restrict__ twf,
                                                 u16* __restrict__ f1) {
    __shared__ u16 HOyo[256 * HO2];   // [y][32o + pad] = 18432 B
    const int tid = threadIdx.x;
    // sibling o-halves of one (b,x) land on the SAME XCD (blk%8 round-robin),
    // 8 blocks apart in dispatch order -> second h read is an L2 hit.
    const int blk = blockIdx.x;
    const int bx = ((blk >> 4) << 3) | (blk & 7);   // b*256 + x
    const int oh = (blk >> 3) & 1;                  // o-half
    const int b = bx >> 8, x = bx & 255;
    const long hbase = ((long)bx) << 14;
    const int lane = tid & 63, wave = tid >> 6;
    const int quad = lane >> 4, col = lane & 15;

    f32x4 acc[2][4];
    const f32x4 z = {0.f, 0.f, 0.f, 0.f};
    #pragma unroll
    for (int i = 0; i < 2; i++)
        #pragma unroll
        for (int j = 0; j < 4; j++) acc[i][j] = z;

    // phase 1: W_hi.h + W_lo.h + g.bas for this o-half
    #pragma unroll
    for (int ks = 0; ks < 2; ks++) {
        bf16x8 B[4], Ah[2], Al[2];
        #pragma unroll
        for (int nt = 0; nt < 4; nt++) {
            const int y = wave * 64 + nt * 16 + col;
            B[nt] = *(const bf16x8*)(h + hbase + (long)y * 64 + ks * 32 + quad * 8);
        }
        #pragma unroll
        for (int mt = 0; mt < 2; mt++) {
            const int og = oh * 32 + mt * 16 + col;
            Ah[mt] = *(const bf16x8*)(wsp + og * 128 + ks * 32 + quad * 8);
            Al[mt] = *(const bf16x8*)(wsp + og * 128 + 64 + ks * 32 + quad * 8);
        }
        #pragma unroll
        for (int mt = 0; mt < 2; mt++)
            #pragma unroll
            for (int nt = 0; nt < 4; nt++) {
                acc[mt][nt] = __builtin_amdgcn_mfma_f32_16x16x32_bf16(Ah[mt], B[nt], acc[mt][nt], 0, 0, 0);
                acc[mt][nt] = __builtin_amdgcn_mfma_f32_16x16x32_bf16(Al[mt], B[nt], acc[mt][nt], 0, 0, 0);
            }
    }
    {
        bf16x8 B[4], Ag[2];
        #pragma unroll
        for (int nt = 0; nt < 4; nt++) {
            const int y = wave * 64 + nt * 16 + col;
            B[nt] = *(const bf16x8*)(bas + y * 32 + quad * 8);
        }
        #pragma unroll
        for (int mt = 0; mt < 2; mt++) {
            const int og = oh * 32 + mt * 16 + col;
            Ag[mt] = *(const bf16x8*)(Gbf + ((long)bx * 64 + og) * 32 + quad * 8);
        }
        #pragma unroll
        for (int mt = 0; mt < 2; mt++)
            #pragma unroll
            for (int nt = 0; nt < 4; nt++)
                acc[mt][nt] = __builtin_amdgcn_mfma_f32_16x16x32_bf16(Ag[mt], B[nt], acc[mt][nt], 0, 0, 0);
    }

    // gelu + pack first (frees acc registers early)
    uint2 pk[8];
    #pragma unroll
    for (int mt = 0; mt < 2; mt++) {
        const float4 cbv = *(const float4*)(cb + oh * 32 + mt * 16 + quad * 4);
        #pragma unroll
        for (int nt = 0; nt < 4; nt++) {
            uint2 w;
            w.x = pack2bf(gelu_fast(acc[mt][nt][0] + cbv.x), gelu_fast(acc[mt][nt][1] + cbv.y));
            w.y = pack2bf(gelu_fast(acc[mt][nt][2] + cbv.z), gelu_fast(acc[mt][nt][3] + cbv.w));
            pk[mt * 4 + nt] = w;
        }
    }
    #pragma unroll
    for (int mt = 0; mt < 2; mt++)
        #pragma unroll
        for (int nt = 0; nt < 4; nt++) {
            const int y = wave * 64 + nt * 16 + col;
            *(uint2*)(HOyo + y * HO2 + mt * 16 + quad * 4) = pk[mt * 4 + nt];
        }
    __syncthreads();

    // h write-back: thread y=tid writes its 32-o slice (64 B, sector-aligned)
    {
        const u16* sr = HOyo + tid * HO2;
        uint2 t[8];
        #pragma unroll
        for (int k = 0; k < 8; k++) t[k] = *(const uint2*)(sr + k * 4);
        u16* dh = h + hbase + (long)tid * 64 + oh * 32;
        #pragma unroll
        for (int q = 0; q < 4; q++) *(uint4*)(dh + q * 8) = ((uint4*)t)[q];
    }

    // DFT-y epilogue for this o-half: waves 0,1 cover 32 o (complete K=256)
    if (wave < 2) {
        f32x4 a0 = z, a1 = z;
        #pragma unroll
        for (int ks = 0; ks < 8; ks++) {
            const int kb = ks * 32 + quad * 8;
            BU bb;
            #pragma unroll
            for (int j = 0; j < 8; j++) bb.s[j] = HOyo[(kb + j) * HO2 + wave * 16 + col];
            const bf16x8 af0 = *(const bf16x8*)(twf + col * 256 + kb);
            const bf16x8 af1 = *(const bf16x8*)(twf + (16 + col) * 256 + kb);
            a0 = __builtin_amdgcn_mfma_f32_16x16x32_bf16(af0, bb.v, a0, 0, 0, 0);
            a1 = __builtin_amdgcn_mfma_f32_16x16x32_bf16(af1, bb.v, a1, 0, 0, 0);
        }
        const int og = oh * 32 + wave * 16 + col;
        u16* dst = f1 + (((long)(b * 64 + og)) * 256 + x) * 32 + quad * 4;
        uint2 w;
        w.x = pack2bf(a0[0], a0[1]); w.y = pack2bf(a0[2], a0[3]);
        *(uint2*)dst = w;
        w.x = pack2bf(a1[0], a1[1]); w.y = pack2bf(a1[2], a1[3]);
        *(uint2*)(dst + 16) = w;
    }
}

// --- K5 (layer 4): conv + fused head, writes d_out only --------------------
__global__ __launch_bounds__(256, 4) void k_conv_head(const u16* __restrict__ h,
                                                      const u16* __restrict__ Gbf,
                                                      const u16* __restrict__ wsp,
                                                      const float* __restrict__ cb,
                                                      const u16* __restrict__ bas,
                                                      const u16* __restrict__ w1sp,
                                                      const float* __restrict__ b1,
                                                      const float* __restrict__ w2,
                                                      const float* __restrict__ b2,
                                                      float* __restrict__ out) {
    __shared__ u16 HOyo[256 * HOP];
    const int tid = threadIdx.x;
    const int b = blockIdx.x >> 8, x = blockIdx.x & 255;
    const long hbase = ((long)(b * 256 + x)) << 14;
    const float bias2 = b2[0];
    const int lane = tid & 63, wave = tid >> 6;
    const int quad = lane >> 4, col = lane & 15;
    f32x4 acc[4][4];
    const f32x4 z = {0.f, 0.f, 0.f, 0.f};
    #pragma unroll
    for (int i = 0; i < 4; i++)
        #pragma unroll
        for (int j = 0; j < 4; j++) acc[i][j] = z;
    #pragma unroll
    for (int ks = 0; ks < 2; ks++) {
        bf16x8 B[4], Ah[4], Al[4];
        #pragma unroll
        for (int nt = 0; nt < 4; nt++) {
            const int y = wave * 64 + nt * 16 + col;
            B[nt] = *(const bf16x8*)(h + hbase + (long)y * 64 + ks * 32 + quad * 8);
        }
        #pragma unroll
        for (int mt = 0; mt < 4; mt++) {
            Ah[mt] = *(const bf16x8*)(wsp + (mt * 16 + col) * 128 + ks * 32 + quad * 8);
            Al[mt] = *(const bf16x8*)(wsp + (mt * 16 + col) * 128 + 64 + ks * 32 + quad * 8);
        }
        #pragma unroll
        for (int mt = 0; mt < 4; mt++)
            #pragma unroll
            for (int nt = 0; nt < 4; nt++) {
                acc[mt][nt] = __builtin_amdgcn_mfma_f32_16x16x32_bf16(Ah[mt], B[nt], acc[mt][nt], 0, 0, 0);
                acc[mt][nt] = __builtin_amdgcn_mfma_f32_16x16x32_bf16(Al[mt], B[nt], acc[mt][nt], 0, 0, 0);
            }
    }
    {
        bf16x8 B[4], Ag[4];
        #pragma unroll
        for (int nt = 0; nt < 4; nt++) {
            const int y = wave * 64 + nt * 16 + col;
            B[nt] = *(const bf16x8*)(bas + y * 32 + quad * 8);
        }
        #pragma unroll
        for (int mt = 0; mt < 4; mt++)
            Ag[mt] = *(const bf16x8*)(Gbf + (((long)(b * 256 + x)) * 64 + mt * 16 + col) * 32 + quad * 8);
        #pragma unroll
        for (int mt = 0; mt < 4; mt++)
            #pragma unroll
            for (int nt = 0; nt < 4; nt++)
                acc[mt][nt] = __builtin_amdgcn_mfma_f32_16x16x32_bf16(Ag[mt], B[nt], acc[mt][nt], 0, 0, 0);
    }
    #pragma unroll
    for (int mt = 0; mt < 4; mt++) {
        const int o0 = mt * 16 + quad * 4;
        const float4 cbv = *(const float4*)(cb + o0);
        #pragma unroll
        for (int nt = 0; nt < 4; nt++) {
            const int y = wave * 64 + nt * 16 + col;
            uint2 w;
            w.x = pack2bf(gelu_fast(acc[mt][nt][0] + cbv.x), gelu_fast(acc[mt][nt][1] + cbv.y));
            w.y = pack2bf(gelu_fast(acc[mt][nt][2] + cbv.z), gelu_fast(acc[mt][nt][3] + cbv.w));
            *(uint2*)(HOyo + y * HOP + o0) = w;
        }
    }
    __syncthreads();
    // head: D[m=f][n=y], K = o (hi | lo), B from HOyo (vector 8B loads)
    f32x4 acc2[4][4];
    #pragma unroll
    for (int i = 0; i < 4; i++)
        #pragma unroll
        for (int j = 0; j < 4; j++) acc2[i][j] = z;
    #pragma unroll
    for (int ks = 0; ks < 4; ks++) {
        const int kk = (ks & 1) * 32 + quad * 8;
        bf16x8 B[4], A[4];
        #pragma unroll
        for (int nt = 0; nt < 4; nt++) {
            const int y = wave * 64 + nt * 16 + col;
            BU bb;
            bb.u2[0] = *(const uint2*)(HOyo + y * HOP + kk);
            bb.u2[1] = *(const uint2*)(HOyo + y * HOP + kk + 4);
            B[nt] = bb.v;
        }
        #pragma unroll
        for (int mt = 0; mt < 4; mt++)
            A[mt] = *(const bf16x8*)(w1sp + (mt * 16 + col) * 128 + ks * 32 + quad * 8);
        #pragma unroll
        for (int mt = 0; mt < 4; mt++)
            #pragma unroll
            for (int nt = 0; nt < 4; nt++)
                acc2[mt][nt] = __builtin_amdgcn_mfma_f32_16x16x32_bf16(A[mt], B[nt], acc2[mt][nt], 0, 0, 0);
    }
    float p4[4] = {0.f, 0.f, 0.f, 0.f};
    #pragma unroll
    for (int mt = 0; mt < 4; mt++) {
        const int f0 = mt * 16 + quad * 4;
        const float4 b1v = *(const float4*)(b1 + f0);
        const float4 w2v = *(const float4*)(w2 + f0);
        #pragma unroll
        for (int r = 0; r < 4; r++) {
            const float bb = (&b1v.x)[r];
            const float ww = (&w2v.x)[r];
            #pragma unroll
            for (int nt = 0; nt < 4; nt++)
                p4[nt] = fmaf(ww, gelu_fast(acc2[mt][nt][r] + bb), p4[nt]);
        }
    }
    #pragma unroll
    for (int nt = 0; nt < 4; nt++) {
        p4[nt] += __shfl_xor(p4[nt], 16);
        p4[nt] += __shfl_xor(p4[nt], 32);
    }
    out[(long)b * 65536 + x * 256 + wave * 64 + lane] = p4[quad] + bias2;
}

extern "C" void kernel_launch(void* const* d_in, const int* in_sizes, int n_in,
                              void* d_out, int out_size, void* d_ws, size_t ws_size,
                              hipStream_t stream) {
    const float* x     = (const float*)d_in[0];
    const float* fc0_w = (const float*)d_in[1];
    const float* fc0_b = (const float*)d_in[2];
    const float* sw[4] = {(const float*)d_in[3], (const float*)d_in[4],
                          (const float*)d_in[5], (const float*)d_in[6]};
    const float* cwA[4] = {(const float*)d_in[7],  (const float*)d_in[9],
                           (const float*)d_in[11], (const float*)d_in[13]};
    const float* cbA[4] = {(const float*)d_in[8],  (const float*)d_in[10],
                           (const float*)d_in[12], (const float*)d_in[14]};
    const float* fc1_w = (const float*)d_in[15];
    const float* fc1_b = (const float*)d_in[16];
    const float* fc2_w = (const float*)d_in[17];
    const float* fc2_b = (const float*)d_in[18];

    char* base = (char*)d_ws;
    u16*   h    = (u16*)base;
    u16*   f1   = (u16*)(base + F1_B);
    u16*   Gbf  = (u16*)(base + G_B);      // also swT (fp32) while G is dead
    float* f2   = (float*)(base + F2_B);
    float* cbuf = (float*)(base + CC_B);
    float* wf   = (float*)(base + WF_B);
    float* wxi  = (float*)(base + WXI_B);
    u16*   twf  = (u16*)(base + TWF_B);
    u16*   bas  = (u16*)(base + BAS_B);
    u16*   wsp  = (u16*)(base + WSP_B);

    k_tab<<<96, 256, 0, stream>>>(wf, wxi, twf, bas);
    k_wsplit<<<80, 256, 0, stream>>>(cwA[0], cwA[1], cwA[2], cwA[3], fc1_w, wsp);
    k_lift<<<4096, 256, 0, stream>>>(x, fc0_w, fc0_b, h, twf, f1);
    for (int l = 0; l < 4; l++) {
        k_swT<<<256, 256, 0, stream>>>(sw[l], (float2*)Gbf);   // G dead here
        k_dftx<<<1024, 256, 0, stream>>>(f1, wf, f2);
        k_mode<<<256, 256, 0, stream>>>(f2, (const float2*)Gbf, cbuf);
        k_invx<<<1024, 256, 0, stream>>>(cbuf, wxi, Gbf);      // overwrites swT
        if (l < 3) {
            k_conv<<<8192, 256, 0, stream>>>(h, Gbf, wsp + l * 8192, cbA[l],
                                             bas, twf, f1);
        } else {
            k_conv_head<<<4096, 256, 0, stream>>>(h, Gbf, wsp + 3 * 8192, cbA[3],
                                                  bas, wsp + 4 * 8192, fc1_b,
                                                  fc2_w, fc2_b, (float*)d_out);
        }
    }
}

// Round 10
// 888.358 us; speedup vs baseline: 1.1618x; 1.1618x over previous
//
#include <hip/hip_runtime.h>
#include <math.h>

// ---------------------------------------------------------------------------
// FNO2d forward, MFMA everywhere, channels-last activations.
// h [b][x][y][i] bf16: conv B-fragments load direct from global; conv C-tile
// -> LDS once (coalesced 128B-row h write-back + DFT-y epilogue MFMAs).
// Conv = full 64o x 256y tile per (b,x) block (round-7 structure: the o-half
// split was falsified twice — FETCH doubles cross-XCD, WRITE triples
// same-XCD from half-line interleaving).
// Spectral chain: coalesced writes; scatters are L2-hot reads. k_mode reads
// sw directly with an XCD-affine m-swizzle (blocks sharing a 64B sw sector
// land on one XCD) — no transpose kernel.
// Workspace (bytes):
//   h    bf16 [16][256][256][64]  @ 0          134,217,728
//   f1   bf16 [(b*64+i)*256+x][32]@ 134217728   16,777,216
//   G    bf16 [b][x][o][kc]       @ 150994944   16,777,216
//   f2   fp32 [bi][m][2]          @ 167772160    2,097,152
//   cc   fp32 [m][b][o][2]        @ 169869312    2,097,152
//   wf   fp32 [x][16k][2]         @ 171966464       32,768
//   wxi  fp32 [k1][x][2]          @ 171999232       32,768
//   twf  bf16 [k2c][y]            @ 172032000       16,384
//   bas  bf16 [y][2k2+c]          @ 172048384       16,384
//   wsp  bf16 [5][64][hi64|lo64]  @ 172064768       81,920
// total 172,146,688 B (~164.2 MiB)
// ---------------------------------------------------------------------------

typedef unsigned int   u32;
typedef unsigned short u16;
typedef __attribute__((ext_vector_type(8))) __bf16 bf16x8;
typedef __attribute__((ext_vector_type(4))) float  f32x4;

constexpr long F1_B  = 134217728;
constexpr long G_B   = 150994944;
constexpr long F2_B  = 167772160;
constexpr long CC_B  = 169869312;
constexpr long WF_B  = 171966464;
constexpr long WXI_B = 171999232;
constexpr long TWF_B = 172032000;
constexpr long BAS_B = 172048384;
constexpr long WSP_B = 172064768;

constexpr int HOP = 76;   // HOyo row pad (u16): 152 B ≡ 0 mod 8

union BU { uint2 u2[2]; uint4 u4; bf16x8 v; u16 s[8]; };

// fast gelu: |erf err| <= 1.5e-7 (A&S 7.1.26); bf16 storage noise dominates.
__device__ __forceinline__ float gelu_fast(float v) {
    const float ax = fabsf(v) * 0.70710678118654752440f;
    const float t = __builtin_amdgcn_rcpf(fmaf(0.3275911f, ax, 1.0f));
    float poly = fmaf(1.061405429f, t, -1.453152027f);
    poly = fmaf(poly, t, 1.421413741f);
    poly = fmaf(poly, t, -0.284496736f);
    poly = fmaf(poly, t, 0.254829592f);
    poly *= t;
    const float pe = poly * __expf(-ax * ax);      // = 1 - erf(ax)
    const float w = (v >= 0.0f) ? (2.0f - pe) : pe;
    return 0.5f * v * w;
}
__device__ __forceinline__ float bflo(u32 u) { return __uint_as_float(u << 16); }
__device__ __forceinline__ float bfhi(u32 u) { return __uint_as_float(u & 0xffff0000u); }
__device__ __forceinline__ u16 f2bf(float f) {            // fp32 -> bf16 RNE
    u32 u = __float_as_uint(f);
    u += 0x7fffu + ((u >> 16) & 1u);
    return (u16)(u >> 16);
}
__device__ __forceinline__ u32 pack2bf(float a, float b) {
    return (u32)f2bf(a) | ((u32)f2bf(b) << 16);
}

// --- tables ----------------------------------------------------------------
__global__ __launch_bounds__(256) void k_tab(float* __restrict__ wf,
                                             float* __restrict__ wxi,
                                             u16* __restrict__ twf,
                                             u16* __restrict__ bas) {
    const int t = blockIdx.x * 256 + threadIdx.x;   // 0..24575
    if (t < 4096) {               // wf[x][k][2] = (cos, -sin)(2*pi*k*x/256)
        const int y = t >> 4, k = t & 15;
        const int m = (k * y) & 255;
        double s, c; sincospi((double)m / 128.0, &s, &c);
        wf[t * 2] = (float)c; wf[t * 2 + 1] = (float)(-s);
    } else if (t < 8192) {        // wxi[k1][x][2] = (cos, +sin)
        const int u = t - 4096;
        const int k1 = u >> 8, x = u & 255;
        const int m = (k1 * x) & 255;
        double s, c; sincospi((double)m / 128.0, &s, &c);
        wxi[u * 2] = (float)c; wxi[u * 2 + 1] = (float)s;
    } else if (t < 16384) {       // twf[k2c][y]: re=cos, im=-sin
        const int u = t - 8192;
        const int kc = u >> 8, y = u & 255;
        const int k2 = kc >> 1;
        const int m = (k2 * y) & 255;
        double s, c; sincospi((double)m / 128.0, &s, &c);
        twf[kc * 256 + y] = f2bf((kc & 1) ? (float)(-s) : (float)c);
    } else {                      // bas[y][2k2+c]: c_k2*cos / -c_k2*sin
        const int u = t - 16384;
        const int y = u >> 5, kc = u & 31;
        const int k2 = kc >> 1;
        const int m = (k2 * y) & 255;
        double s, c; sincospi((double)m / 128.0, &s, &c);
        const float cc = (k2 == 0) ? 1.0f : 2.0f;
        bas[y * 32 + kc] = f2bf((kc & 1) ? (float)(-cc * s) : (float)(cc * c));
    }
}

// --- weight split: wsp[w][o][0..63]=hi, [o][64..127]=lo --------------------
__global__ __launch_bounds__(256) void k_wsplit(const float* __restrict__ c1,
                                                const float* __restrict__ c2,
                                                const float* __restrict__ c3,
                                                const float* __restrict__ c4,
                                                const float* __restrict__ f1w,
                                                u16* __restrict__ wsp) {
    const int t = blockIdx.x * 256 + threadIdx.x;   // < 20480
    const int w = t >> 12, p = t & 4095;
    const float* src = (w == 0) ? c1 : (w == 1) ? c2 : (w == 2) ? c3
                     : (w == 3) ? c4 : f1w;
    const float f = src[p];
    const u16 hi = f2bf(f);
    const u16 lo = f2bf(f - __uint_as_float((u32)hi << 16));
    u16* dst = wsp + w * 8192 + (p >> 6) * 128 + (p & 63);
    dst[0]  = hi;
    dst[64] = lo;
}

// --- full-tile DFT-y epilogue: f1 rows from HOyo[y][o], o = 64 -------------
__device__ __forceinline__ void f1t_epilogue(const u16* HOyo,
                                             const u16* __restrict__ twf,
                                             u16* __restrict__ f1,
                                             int b, int x, int tid) {
    const int lane = tid & 63, wave = tid >> 6;
    const int quad = lane >> 4, col = lane & 15;
    const int o = wave * 16 + col;
    f32x4 a0 = {0.f, 0.f, 0.f, 0.f}, a1 = {0.f, 0.f, 0.f, 0.f};
    #pragma unroll
    for (int ks = 0; ks < 8; ks++) {
        const int kb = ks * 32 + quad * 8;
        BU bb;
        #pragma unroll
        for (int j = 0; j < 8; j++) bb.s[j] = HOyo[(kb + j) * HOP + o];
        const bf16x8 af0 = *(const bf16x8*)(twf + col * 256 + kb);
        const bf16x8 af1 = *(const bf16x8*)(twf + (16 + col) * 256 + kb);
        a0 = __builtin_amdgcn_mfma_f32_16x16x32_bf16(af0, bb.v, a0, 0, 0, 0);
        a1 = __builtin_amdgcn_mfma_f32_16x16x32_bf16(af1, bb.v, a1, 0, 0, 0);
    }
    u16* dst = f1 + (((long)(b * 64 + o)) * 256 + x) * 32 + quad * 4;
    uint2 w;
    w.x = pack2bf(a0[0], a0[1]); w.y = pack2bf(a0[2], a0[3]);
    *(uint2*)dst = w;
    w.x = pack2bf(a1[0], a1[1]); w.y = pack2bf(a1[2], a1[3]);
    *(uint2*)(dst + 16) = w;
}

// --- lift: h[b][x][y][i] = fc0(x), channels-last, + DFT-y epilogue ---------
__global__ __launch_bounds__(256) void k_lift(const float* __restrict__ xin,
                                              const float* __restrict__ w0,
                                              const float* __restrict__ b0,
                                              u16* __restrict__ h,
                                              const u16* __restrict__ twf,
                                              u16* __restrict__ f1) {
    __shared__ float ws0[192], bs0[64];
    __shared__ u16 HOyo[256 * HOP];
    const int tid = threadIdx.x;
    if (tid < 192) ws0[tid] = w0[tid];
    if (tid < 64)  bs0[tid] = b0[tid];
    __syncthreads();
    const int b = blockIdx.x >> 8, x = blockIdx.x & 255;
    const long pix = (((long)b * 3) * 256 + x) * 256 + tid;
    const float x0 = xin[pix];
    const float x1 = xin[pix + 65536];
    const float x2 = xin[pix + 131072];
    u32 pr[32];
    #pragma unroll
    for (int w = 0; w < 64; w += 2) {
        float v0 = bs0[w], v1 = bs0[w + 1];
        v0 = fmaf(x0, ws0[w * 3],     v0);  v1 = fmaf(x0, ws0[w * 3 + 3], v1);
        v0 = fmaf(x1, ws0[w * 3 + 1], v0);  v1 = fmaf(x1, ws0[w * 3 + 4], v1);
        v0 = fmaf(x2, ws0[w * 3 + 2], v0);  v1 = fmaf(x2, ws0[w * 3 + 5], v1);
        pr[w >> 1] = pack2bf(v0, v1);
    }
    u16* hrow = h + (((long)(b * 256 + x)) << 14) + (long)tid * 64;
    #pragma unroll
    for (int q = 0; q < 8; q++) *(uint4*)(hrow + q * 8) = ((uint4*)pr)[q];
    #pragma unroll
    for (int q = 0; q < 16; q++)
        *(uint2*)(HOyo + tid * HOP + q * 4) = ((uint2*)pr)[q];
    __syncthreads();
    f1t_epilogue(HOyo, twf, f1, b, x, tid);
}

// --- K2: f2[bi][m] = sum_x F1[bi][x][k2] * wf[x][k1]   (m = k1*16+k2) ------
__global__ __launch_bounds__(256) void k_dftx(const u16* __restrict__ f1,
                                              const float* __restrict__ wf,
                                              float* __restrict__ f2) {
    __shared__ u32 fsh[4096];   // [x][16] re/im bf16 pairs
    const int tid = threadIdx.x;
    const uint4* src = (const uint4*)(f1 + (long)blockIdx.x * 8192);
    uint4* dst = (uint4*)fsh;
    #pragma unroll
    for (int q = 0; q < 4; q++) dst[q * 256 + tid] = src[q * 256 + tid];
    __syncthreads();
    const int k1 = tid >> 4, k2 = tid & 15;
    float cr0 = 0, ci0 = 0, cr1 = 0, ci1 = 0;
    for (int x = 0; x < 256; x += 2) {
        const u32 wa = fsh[x * 16 + k2];
        const float2 ta = *(const float2*)(wf + x * 32 + k1 * 2);
        const float Far = bflo(wa), Fai = bfhi(wa);
        cr0 = fmaf(Far, ta.x, fmaf(-Fai, ta.y, cr0));
        ci0 = fmaf(Fai, ta.x, fmaf(Far, ta.y, ci0));
        const u32 wb = fsh[(x + 1) * 16 + k2];
        const float2 tb = *(const float2*)(wf + (x + 1) * 32 + k1 * 2);
        const float Fbr = bflo(wb), Fbi = bfhi(wb);
        cr1 = fmaf(Fbr, tb.x, fmaf(-Fbi, tb.y, cr1));
        ci1 = fmaf(Fbi, tb.x, fmaf(Fbr, tb.y, ci1));
    }
    *(float2*)(f2 + ((long)blockIdx.x * 256 + tid) * 2) =
        make_float2(cr0 + cr1, ci0 + ci1);
}

// --- K3: cc[m][b][o] = sum_i f2[b*64+i][m] * sw[i*64+o][m] / 65536 ---------
// sw read directly (strided 8B); XCD-affine m-swizzle: the 8 blocks sharing
// each 64B sw sector (consecutive m) land on ONE XCD -> sw fetched ~once.
__global__ __launch_bounds__(256) void k_mode(const float* __restrict__ f2,
                                              const float* __restrict__ sw,
                                              float* __restrict__ cc) {
    __shared__ float2 wsh[4096];   // [i*64+o], pre-scaled
    __shared__ float2 fsh[1024];   // [b*64+i]
    const int tid = threadIdx.x;
    const int blk = blockIdx.x;
    const int m = (blk >> 3) | ((blk & 7) << 5);   // XCD c gets m in [32c,32c+32)
    const float scale = 1.0f / 65536.0f;
    for (int p = tid; p < 4096; p += 256) {
        const float2 w = *(const float2*)(sw + ((long)p * 256 + m) * 2);
        wsh[p] = make_float2(w.x * scale, w.y * scale);
    }
    for (int t = tid; t < 1024; t += 256)
        fsh[t] = *(const float2*)(f2 + ((long)t * 256 + m) * 2);
    __syncthreads();
    const int b = tid >> 4, o0 = (tid & 15) * 4;
    float re[4] = {0, 0, 0, 0}, im[4] = {0, 0, 0, 0};
    for (int i = 0; i < 64; i++) {
        const float2 F = fsh[b * 64 + i];
        #pragma unroll
        for (int oo = 0; oo < 4; oo++) {
            const float2 W = wsh[i * 64 + o0 + oo];
            re[oo] = fmaf(F.x, W.x, fmaf(-F.y, W.y, re[oo]));
            im[oo] = fmaf(F.x, W.y, fmaf(F.y, W.x, im[oo]));
        }
    }
    #pragma unroll
    for (int oo = 0; oo < 4; oo++)
        *(float2*)(cc + ((long)m * 1024 + b * 64 + o0 + oo) * 2) =
            make_float2(re[oo], im[oo]);
}

// --- K4: G[b][x][o][kc]; block = (b, o); cc gather from L2 -----------------
__global__ __launch_bounds__(256) void k_invx(const float* __restrict__ cc,
                                              const float* __restrict__ wxi,
                                              u16* __restrict__ g) {
    __shared__ float2 csh[256];       // [m]
    const int tid = threadIdx.x;
    const int b = blockIdx.x >> 6, o = blockIdx.x & 63;
    csh[tid] = *(const float2*)(cc + ((long)tid * 1024 + b * 64 + o) * 2);
    __syncthreads();
    const int x = tid;
    float ar[16], ai[16];
    #pragma unroll
    for (int k = 0; k < 16; k++) { ar[k] = 0; ai[k] = 0; }
    for (int k1 = 0; k1 < 16; k1++) {
        const float2 t = *(const float2*)(wxi + (k1 * 256 + x) * 2);
        #pragma unroll
        for (int k2 = 0; k2 < 16; k2++) {
            const float2 C = csh[k1 * 16 + k2];
            ar[k2] = fmaf(C.x, t.x, fmaf(-C.y, t.y, ar[k2]));
            ai[k2] = fmaf(C.x, t.y, fmaf(C.y, t.x, ai[k2]));
        }
    }
    u32 wbuf[16];
    #pragma unroll
    for (int k = 0; k < 16; k++) wbuf[k] = pack2bf(ar[k], ai[k]);
    u16* ob = g + ((long)(b * 256 + x) * 64 + o) * 32;   // 64 B, sector-aligned
    #pragma unroll
    for (int q = 0; q < 4; q++) *(uint4*)(ob + q * 8) = ((uint4*)wbuf)[q];
}

// --- conv phase 1: acc[mt][nt] = W_hi.h + W_lo.h + g.bas  (all direct) -----
__device__ __forceinline__ void conv_phase1(const u16* __restrict__ h, long hbase,
                                            const u16* __restrict__ Gbf,
                                            const u16* __restrict__ wsp,
                                            const u16* __restrict__ bas,
                                            int b, int x, int tid, f32x4 (*acc)[4]) {
    const int lane = tid & 63, wave = tid >> 6;
    const int quad = lane >> 4, col = lane & 15;
    #pragma unroll
    for (int ks = 0; ks < 2; ks++) {
        bf16x8 B[4], Ah[4], Al[4];
        #pragma unroll
        for (int nt = 0; nt < 4; nt++) {
            const int y = wave * 64 + nt * 16 + col;
            B[nt] = *(const bf16x8*)(h + hbase + (long)y * 64 + ks * 32 + quad * 8);
        }
        #pragma unroll
        for (int mt = 0; mt < 4; mt++) {
            Ah[mt] = *(const bf16x8*)(wsp + (mt * 16 + col) * 128 + ks * 32 + quad * 8);
            Al[mt] = *(const bf16x8*)(wsp + (mt * 16 + col) * 128 + 64 + ks * 32 + quad * 8);
        }
        #pragma unroll
        for (int mt = 0; mt < 4; mt++)
            #pragma unroll
            for (int nt = 0; nt < 4; nt++) {
                acc[mt][nt] = __builtin_amdgcn_mfma_f32_16x16x32_bf16(Ah[mt], B[nt], acc[mt][nt], 0, 0, 0);
                acc[mt][nt] = __builtin_amdgcn_mfma_f32_16x16x32_bf16(Al[mt], B[nt], acc[mt][nt], 0, 0, 0);
            }
    }
    {   // spectral: A = g rows (contiguous layout [b][x][o][kc]), B = bas
        bf16x8 B[4], Ag[4];
        #pragma unroll
        for (int nt = 0; nt < 4; nt++) {
            const int y = wave * 64 + nt * 16 + col;
            B[nt] = *(const bf16x8*)(bas + y * 32 + quad * 8);
        }
        #pragma unroll
        for (int mt = 0; mt < 4; mt++)
            Ag[mt] = *(const bf16x8*)(Gbf + (((long)(b * 256 + x)) * 64 + mt * 16 + col) * 32 + quad * 8);
        #pragma unroll
        for (int mt = 0; mt < 4; mt++)
            #pragma unroll
            for (int nt = 0; nt < 4; nt++)
                acc[mt][nt] = __builtin_amdgcn_mfma_f32_16x16x32_bf16(Ag[mt], B[nt], acc[mt][nt], 0, 0, 0);
    }
}

// --- K5 (layers 1-3): h = gelu(spec+conv+cb) in place + DFT-y epilogue -----
__global__ __launch_bounds__(256, 4) void k_conv(u16* __restrict__ h,
                                                 const u16* __restrict__ Gbf,
                                                 const u16* __restrict__ wsp,
                                                 const float* __restrict__ cb,
                                                 const u16* __restrict__ bas,
                                                 const u16* __restrict__ twf,
                                                 u16* __restrict__ f1) {
    __shared__ u16 HOyo[256 * HOP];
    const int tid = threadIdx.x;
    const int b = blockIdx.x >> 8, x = blockIdx.x & 255;
    const long hbase = ((long)(b * 256 + x)) << 14;
    f32x4 acc[4][4];
    const f32x4 z = {0.f, 0.f, 0.f, 0.f};
    #pragma unroll
    for (int i = 0; i < 4; i++)
        #pragma unroll
        for (int j = 0; j < 4; j++) acc[i][j] = z;
    conv_phase1(h, hbase, Gbf, wsp, bas, b, x, tid, acc);
    const int lane = tid & 63, wave = tid >> 6;
    const int quad = lane >> 4, col = lane & 15;
    #pragma unroll
    for (int mt = 0; mt < 4; mt++) {
        const int o0 = mt * 16 + quad * 4;
        const float4 cbv = *(const float4*)(cb + o0);
        #pragma unroll
        for (int nt = 0; nt < 4; nt++) {
            const int y = wave * 64 + nt * 16 + col;
            uint2 w;
            w.x = pack2bf(gelu_fast(acc[mt][nt][0] + cbv.x), gelu_fast(acc[mt][nt][1] + cbv.y));
            w.y = pack2bf(gelu_fast(acc[mt][nt][2] + cbv.z), gelu_fast(acc[mt][nt][3] + cbv.w));
            *(uint2*)(HOyo + y * HOP + o0) = w;
        }
    }
    __syncthreads();
    // coalesced h write-back: one 128 B row per thread, from LDS
    {
        uint2 tmp[16];
        const u16* sr = HOyo + tid * HOP;
        #pragma unroll
        for (int k = 0; k < 16; k++) tmp[k] = *(const uint2*)(sr + k * 4);
        u16* dh = h + hbase + (long)tid * 64;
        #pragma unroll
        for (int q = 0; q < 8; q++) *(uint4*)(dh + q * 8) = ((uint4*)tmp)[q];
    }
    f1t_epilogue(HOyo, twf, f1, b, x, tid);
}

// --- K5 (layer 4): conv + fused head, writes d_out only --------------------
__global__ __launch_bounds__(256, 4) void k_conv_head(const u16* __restrict__ h,
                                                      const u16* __restrict__ Gbf,
                                                      const u16* __restrict__ wsp,
                                                      const float* __restrict__ cb,
                                                      const u16* __restrict__ bas,
                                                      const u16* __restrict__ w1sp,
                                                      const float* __restrict__ b1,
                                                      const float* __restrict__ w2,
                                                      const float* __restrict__ b2,
                                                      float* __restrict__ out) {
    __shared__ u16 HOyo[256 * HOP];
    const int tid = threadIdx.x;
    const int b = blockIdx.x >> 8, x = blockIdx.x & 255;
    const long hbase = ((long)(b * 256 + x)) << 14;
    const float bias2 = b2[0];
    const int lane = tid & 63, wave = tid >> 6;
    const int quad = lane >> 4, col = lane & 15;
    f32x4 acc[4][4];
    const f32x4 z = {0.f, 0.f, 0.f, 0.f};
    #pragma unroll
    for (int i = 0; i < 4; i++)
        #pragma unroll
        for (int j = 0; j < 4; j++) acc[i][j] = z;
    conv_phase1(h, hbase, Gbf, wsp, bas, b, x, tid, acc);
    #pragma unroll
    for (int mt = 0; mt < 4; mt++) {
        const int o0 = mt * 16 + quad * 4;
        const float4 cbv = *(const float4*)(cb + o0);
        #pragma unroll
        for (int nt = 0; nt < 4; nt++) {
            const int y = wave * 64 + nt * 16 + col;
            uint2 w;
            w.x = pack2bf(gelu_fast(acc[mt][nt][0] + cbv.x), gelu_fast(acc[mt][nt][1] + cbv.y));
            w.y = pack2bf(gelu_fast(acc[mt][nt][2] + cbv.z), gelu_fast(acc[mt][nt][3] + cbv.w));
            *(uint2*)(HOyo + y * HOP + o0) = w;
        }
    }
    __syncthreads();
    // head: D[m=f][n=y], K = o (hi | lo), B from HOyo (vector 8B loads)
    f32x4 acc2[4][4];
    #pragma unroll
    for (int i = 0; i < 4; i++)
        #pragma unroll
        for (int j = 0; j < 4; j++) acc2[i][j] = z;
    #pragma unroll
    for (int ks = 0; ks < 4; ks++) {
        const int kk = (ks & 1) * 32 + quad * 8;
        bf16x8 B[4], A[4];
        #pragma unroll
        for (int nt = 0; nt < 4; nt++) {
            const int y = wave * 64 + nt * 16 + col;
            BU bb;
            bb.u2[0] = *(const uint2*)(HOyo + y * HOP + kk);
            bb.u2[1] = *(const uint2*)(HOyo + y * HOP + kk + 4);
            B[nt] = bb.v;
        }
        #pragma unroll
        for (int mt = 0; mt < 4; mt++)
            A[mt] = *(const bf16x8*)(w1sp + (mt * 16 + col) * 128 + ks * 32 + quad * 8);
        #pragma unroll
        for (int mt = 0; mt < 4; mt++)
            #pragma unroll
            for (int nt = 0; nt < 4; nt++)
                acc2[mt][nt] = __builtin_amdgcn_mfma_f32_16x16x32_bf16(A[mt], B[nt], acc2[mt][nt], 0, 0, 0);
    }
    float p4[4] = {0.f, 0.f, 0.f, 0.f};
    #pragma unroll
    for (int mt = 0; mt < 4; mt++) {
        const int f0 = mt * 16 + quad * 4;
        const float4 b1v = *(const float4*)(b1 + f0);
        const float4 w2v = *(const float4*)(w2 + f0);
        #pragma unroll
        for (int r = 0; r < 4; r++) {
            const float bb = (&b1v.x)[r];
            const float ww = (&w2v.x)[r];
            #pragma unroll
            for (int nt = 0; nt < 4; nt++)
                p4[nt] = fmaf(ww, gelu_fast(acc2[mt][nt][r] + bb), p4[nt]);
        }
    }
    #pragma unroll
    for (int nt = 0; nt < 4; nt++) {
        p4[nt] += __shfl_xor(p4[nt], 16);
        p4[nt] += __shfl_xor(p4[nt], 32);
    }
    out[(long)b * 65536 + x * 256 + wave * 64 + lane] = p4[quad] + bias2;
}

extern "C" void kernel_launch(void* const* d_in, const int* in_sizes, int n_in,
                              void* d_out, int out_size, void* d_ws, size_t ws_size,
                              hipStream_t stream) {
    const float* x     = (const float*)d_in[0];
    const float* fc0_w = (const float*)d_in[1];
    const float* fc0_b = (const float*)d_in[2];
    const float* sw[4] = {(const float*)d_in[3], (const float*)d_in[4],
                          (const float*)d_in[5], (const float*)d_in[6]};
    const float* cwA[4] = {(const float*)d_in[7],  (const float*)d_in[9],
                           (const float*)d_in[11], (const float*)d_in[13]};
    const float* cbA[4] = {(const float*)d_in[8],  (const float*)d_in[10],
                           (const float*)d_in[12], (const float*)d_in[14]};
    const float* fc1_w = (const float*)d_in[15];
    const float* fc1_b = (const float*)d_in[16];
    const float* fc2_w = (const float*)d_in[17];
    const float* fc2_b = (const float*)d_in[18];

    char* base = (char*)d_ws;
    u16*   h    = (u16*)base;
    u16*   f1   = (u16*)(base + F1_B);
    u16*   Gbf  = (u16*)(base + G_B);
    float* f2   = (float*)(base + F2_B);
    float* cbuf = (float*)(base + CC_B);
    float* wf   = (float*)(base + WF_B);
    float* wxi  = (float*)(base + WXI_B);
    u16*   twf  = (u16*)(base + TWF_B);
    u16*   bas  = (u16*)(base + BAS_B);
    u16*   wsp  = (u16*)(base + WSP_B);

    k_tab<<<96, 256, 0, stream>>>(wf, wxi, twf, bas);
    k_wsplit<<<80, 256, 0, stream>>>(cwA[0], cwA[1], cwA[2], cwA[3], fc1_w, wsp);
    k_lift<<<4096, 256, 0, stream>>>(x, fc0_w, fc0_b, h, twf, f1);
    for (int l = 0; l < 4; l++) {
        k_dftx<<<1024, 256, 0, stream>>>(f1, wf, f2);
        k_mode<<<256, 256, 0, stream>>>(f2, sw[l], cbuf);
        k_invx<<<1024, 256, 0, stream>>>(cbuf, wxi, Gbf);
        if (l < 3) {
            k_conv<<<4096, 256, 0, stream>>>(h, Gbf, wsp + l * 8192, cbA[l],
                                             bas, twf, f1);
        } else {
            k_conv_head<<<4096, 256, 0, stream>>>(h, Gbf, wsp + 3 * 8192, cbA[3],
                                                  bas, wsp + 4 * 8192, fc1_b,
                                                  fc2_w, fc2_b, (float*)d_out);
        }
    }
}